// Round 10
// baseline (240.084 us; speedup 1.0000x reference)
//
#include <hip/hip_runtime.h>
#include <hip/hip_bf16.h>
#include <math.h>

#define N_   64
#define C_   64
#define T_   128
#define V_   25
#define OUT_ 64
#define REL_ 8
#define MID_ 32
#define TV_  (T_*V_)   // 3200
#define VV_  (V_*V_)   // 625
#define TT2  8         // t-tile for fused temporal kernel

typedef __hip_bfloat16 bf16;
typedef unsigned int uint;
__device__ __forceinline__ float b2f(bf16 x){ return __bfloat162float(x); }
__device__ __forceinline__ bf16  f2b(float x){ return __float2bfloat16(x); }
__device__ __forceinline__ float bfu(uint u){ return __uint_as_float(u<<16); }
__device__ __forceinline__ float bfh(uint u){ return __uint_as_float(u&0xffff0000u); }
__device__ __forceinline__ float bfs(unsigned short s){ return __uint_as_float(((uint)s)<<16); }

// LESSONS (measured, R4-R9):
//  * k10 carries acc[25]/thread -> needs ~156 VGPR naturally. ANY min-waves
//    launch_bounds cap forces 64-84 VGPR -> scratch spill -> ~1.1GB HBM
//    scratch traffic, 2.5-4x slowdown (R6/R7/R8). k10 stays plain (256).
//  * R4 staging structure (inside-round, after phase-1 compute) is clean.
//  * R9: attc/x1c materialization (2x102MB fp32) cost ~614MB of HBM traffic
//    across k4/k6/k8/k_comb -> eliminated algebraically this round.

// K0: one-time transpose of the 5 conv weight matrices into WTg[c][96] (+ biases Bg[96])
__global__ __launch_bounds__(256) void k0_prep(
    const float* __restrict__ w1, const float* __restrict__ b1,
    const float* __restrict__ w2, const float* __restrict__ b2,
    const float* __restrict__ w11, const float* __restrict__ b11,
    const float* __restrict__ w22, const float* __restrict__ b22,
    const float* __restrict__ w3, const float* __restrict__ b3,
    float* __restrict__ WTg, float* __restrict__ Bg)
{
    int tid = threadIdx.x;
    for (int e = tid; e < 96*C_; e += 256){
        int o = e / C_, c = e % C_;
        float w;
        if      (o < 8)  w = w1[o*C_+c];
        else if (o < 16) w = w2[(o-8)*C_+c];
        else if (o < 24) w = w11[(o-16)*C_+c];
        else if (o < 32) w = w22[(o-24)*C_+c];
        else             w = w3[(o-32)*C_+c];
        WTg[c*96 + o] = w;
    }
    if (tid < 96){
        int o = tid; float bb;
        if      (o < 8)  bb = b1[o];
        else if (o < 16) bb = b2[o-8];
        else if (o < 24) bb = b11[o-16];
        else if (o < 32) bb = b22[o-24];
        else             bb = b3[o-32];
        Bg[o] = bb;
    }
}

// K1: all five 1x1 convs. block = (n, 64-wide j tile); thread = 6 o x 4 j micro-tile.
__global__ __launch_bounds__(256) void k1_convs(
    const float* __restrict__ x,
    const float* __restrict__ WTg, const float* __restrict__ Bg,
    float* __restrict__ x1f, float* __restrict__ x2f,
    float* __restrict__ x11f, float* __restrict__ x22f,
    bf16* __restrict__ x3h)
{
    __shared__ __align__(16) float xl[C_*64];    // 16KB
    __shared__ __align__(16) float WTl[C_*96];   // 24KB
    __shared__ float Bl[96];
    int bid = blockIdx.x;
    int n = bid / 50, jt = bid % 50;
    int j0 = jt * 64;
    int tid = threadIdx.x;
    for (int e = tid; e < 1024; e += 256){
        int c = e >> 4, j4 = e & 15;
        ((float4*)xl)[e] = ((const float4*)(x + (size_t)(n*C_+c)*TV_ + j0))[j4];
    }
    for (int e = tid; e < 1536; e += 256)
        ((float4*)WTl)[e] = ((const float4*)WTg)[e];
    if (tid < 96) Bl[tid] = Bg[tid];
    __syncthreads();

    int og = tid >> 4;
    int jg = tid & 15;
    int o0 = og*6, jj = jg*4;
    float acc[6][4];
    #pragma unroll
    for (int i=0;i<6;i++){
        float b = Bl[o0+i];
        #pragma unroll
        for (int q=0;q<4;q++) acc[i][q] = b;
    }
    #pragma unroll 8
    for (int c = 0; c < C_; ++c){
        float4 xv = *(const float4*)&xl[c*64 + jj];
        #pragma unroll
        for (int i=0;i<6;i++){
            float w = WTl[c*96 + o0 + i];
            acc[i][0] = fmaf(w, xv.x, acc[i][0]);
            acc[i][1] = fmaf(w, xv.y, acc[i][1]);
            acc[i][2] = fmaf(w, xv.z, acc[i][2]);
            acc[i][3] = fmaf(w, xv.w, acc[i][3]);
        }
    }
    int pos = j0 + jj;
    #pragma unroll
    for (int i=0;i<6;i++){
        int o = o0 + i;
        float4 v = make_float4(acc[i][0], acc[i][1], acc[i][2], acc[i][3]);
        if      (o < 8)  *(float4*)&x1f [(size_t)(n*REL_+o)     *TV_ + pos] = v;
        else if (o < 16) *(float4*)&x2f [(size_t)(n*REL_+(o-8)) *TV_ + pos] = v;
        else if (o < 24) *(float4*)&x11f[(size_t)(n*REL_+(o-16))*TV_ + pos] = v;
        else if (o < 32) *(float4*)&x22f[(size_t)(n*REL_+(o-24))*TV_ + pos] = v;
        else {
            bf16 h0=f2b(v.x), h1=f2b(v.y), h2=f2b(v.z), h3=f2b(v.w);
            ushort4 pk;
            pk.x = *(unsigned short*)&h0; pk.y = *(unsigned short*)&h1;
            pk.z = *(unsigned short*)&h2; pk.w = *(unsigned short*)&h3;
            *(ushort4*)&x3h[(size_t)(n*OUT_+(o-32))*TV_ + pos] = pk;
        }
    }
}

// Kx3bar: x3bar[n,c,v] = mean_t x3[n,c,t,v]
__global__ __launch_bounds__(128) void k_x3bar(const bf16* __restrict__ x3h,
                                               float* __restrict__ x3bar)
{
    __shared__ float red[128*26];
    int bid = blockIdx.x;   // n*OUT + c
    int t = threadIdx.x;
    const bf16* row = x3h + (size_t)bid*TV_ + t*V_;
    #pragma unroll
    for (int v=0;v<V_;++v) red[t*26+v] = b2f(row[v]);
    __syncthreads();
    for (int s=64; s>0; s>>=1){
        if (t < s){
            #pragma unroll
            for (int v=0;v<V_;++v) red[t*26+v] += red[(t+s)*26+v];
        }
        __syncthreads();
    }
    if (t < V_) x3bar[(size_t)bid*V_+t] = red[t] * (1.0f/T_);
}

// K3: att8 = tanh(x1^T x2 / T);  xm = tanh(w5_0*mean_res + w5_1*max_res + b5)*alpha
__global__ __launch_bounds__(256) void k3_att8_xm(
    const float* __restrict__ x1f, const float* __restrict__ x2f,
    const float* __restrict__ w5, const float* __restrict__ b5,
    const int* __restrict__ alpha,
    float* __restrict__ att8, float* __restrict__ xm)
{
    __shared__ __align__(16) float l1[TV_], l2[TV_];
    __shared__ float mu1l[V_], mu2l[V_], m1l[V_], m2l[V_];
    int bid = blockIdx.x;      // n*REL + r
    int tid = threadIdx.x;
    int r = bid % REL_;
    for (int e = tid; e < 800; e += 256){
        ((float4*)l1)[e] = ((const float4*)(x1f + (size_t)bid*TV_))[e];
        ((float4*)l2)[e] = ((const float4*)(x2f + (size_t)bid*TV_))[e];
    }
    __syncthreads();
    if (tid < 50){
        int v = tid % V_;
        const float* L = (tid < V_) ? l1 : l2;
        float s=0.f, mm=-1e30f;
        for (int t=0;t<T_;++t){
            float a = L[t*V_+v];
            s += a; mm = fmaxf(mm, a);
        }
        if (tid < V_){ mu1l[v]=s*(1.0f/T_); m1l[v]=mm; }
        else         { mu2l[v]=s*(1.0f/T_); m2l[v]=mm; }
    }
    __syncthreads();
    float w50=w5[r*2+0], w51=w5[r*2+1], b5r=b5[r];
    float af = (float)alpha[0];
    for (int idx=tid; idx<VV_; idx+=256){
        int u = idx/V_, v = idx%V_;
        float s=0.f;
        for (int t=0;t<T_;++t) s = fmaf(l1[t*V_+u], l2[t*V_+v], s);
        att8[(size_t)bid*VV_+idx] = tanhf(s*(1.0f/T_));
        float mr = mu1l[u]-mu2l[v];
        float xr = m1l[u]-m2l[v];
        xm[(size_t)bid*VV_+idx] = tanhf(fmaf(w50,mr,fmaf(w51,xr,b5r))) * af;
    }
}

// K6v2: g[n,c] = (1/V)(sum_r watt[c,r]*<x3bar[c], rowsum(att8_r)> + V*batt[c]*sum(x3bar[c]))
//        then channel attention chain (1x1 -> BN -> GELU -> 1x1 -> sigmoid).
// No attc materialization.
__global__ __launch_bounds__(256) void k6_chatt2(
    const float* __restrict__ att8, const float* __restrict__ x3bar,
    const float* __restrict__ watt, const float* __restrict__ batt,
    const float* __restrict__ wc1, const float* __restrict__ bc1,
    const float* __restrict__ bng, const float* __restrict__ bnb,
    const float* __restrict__ bnm, const float* __restrict__ bnv,
    const float* __restrict__ wc2, const float* __restrict__ bc2,
    float* __restrict__ catt)
{
    __shared__ float rs8[REL_*V_];
    __shared__ float gl[OUT_];
    __shared__ float hl[MID_];
    int n = blockIdx.x, tid = threadIdx.x;
    if (tid < REL_*V_){
        int r = tid / V_, u = tid % V_;
        const float* p = att8 + (size_t)(n*REL_+r)*VV_ + u*V_;
        float s = 0.f;
        #pragma unroll
        for (int v=0;v<V_;++v) s += p[v];
        rs8[tid] = s;
    }
    __syncthreads();
    if (tid < OUT_){
        int c = tid;
        const float* xb = x3bar + (size_t)(n*OUT_+c)*V_;
        float xbr[V_], sb = 0.f;
        #pragma unroll
        for (int u=0;u<V_;++u){ xbr[u]=xb[u]; sb += xbr[u]; }
        float s = 0.f;
        #pragma unroll
        for (int r=0;r<REL_;++r){
            float d = 0.f;
            #pragma unroll
            for (int u=0;u<V_;++u) d = fmaf(xbr[u], rs8[r*V_+u], d);
            s = fmaf(watt[c*REL_+r], d, s);
        }
        gl[c] = (s + (float)V_*batt[c]*sb) * (1.0f/(float)V_);
    }
    __syncthreads();
    if (tid < MID_){
        float h = bc1[tid];
        for (int c=0;c<OUT_;++c) h = fmaf(wc1[tid*OUT_+c], gl[c], h);
        h = (h - bnm[tid]) * bng[tid] * rsqrtf(bnv[tid] + 1e-5f) + bnb[tid];
        h = 0.5f*h*(1.0f+erff(h*0.70710678118654752f));
        hl[tid]=h;
    }
    __syncthreads();
    if (tid < OUT_){
        float s = bc2[tid];
        for (int m=0;m<MID_;++m) s = fmaf(wc2[tid*MID_+m], hl[m], s);
        catt[n*OUT_+tid] = 1.0f/(1.0f+expf(-s));
    }
}

// K8v3: s_att via c-sum pushed inward (no x1c read):
//  W[r,v]=sum_c scl*w4[c,r]*x3bar[c,v]; Y[v]=sum_c scl*x3bar[c,v];
//  beta=sum_c scl*b4[c]*sum_v x3bar[c,v];
//  acc[u]=sum_{r,v} xm[r,u,v]*W[r,v] + sum_v A[u,v]*Y[v] + beta.
__global__ __launch_bounds__(256) void k8_satt3(
    const float* __restrict__ xm, const float* __restrict__ A,
    const float* __restrict__ catt, const float* __restrict__ x3bar,
    const float* __restrict__ w4, const float* __restrict__ b4,
    const float* __restrict__ wsp, const float* __restrict__ bsp,
    float* __restrict__ satt)
{
    __shared__ __align__(16) float xml[REL_*VV_];  // 20KB
    __shared__ __align__(16) float xbl[OUT_*V_];   // 6.4KB
    __shared__ float Al[VV_];
    __shared__ float w4l[OUT_*REL_];
    __shared__ float scl[OUT_];
    __shared__ float Wl[REL_*V_];
    __shared__ float Yl[V_];
    __shared__ float red[OUT_];
    int n = blockIdx.x, tid = threadIdx.x;
    for (int e=tid; e<1250; e+=256)
        ((float4*)xml)[e] = ((const float4*)(xm + (size_t)n*REL_*VV_))[e];
    for (int e=tid; e<400; e+=256)
        ((float4*)xbl)[e] = ((const float4*)(x3bar + (size_t)n*OUT_*V_))[e];
    for (int e=tid; e<VV_; e+=256) Al[e] = A[e];
    for (int e=tid; e<OUT_*REL_; e+=256) w4l[e] = w4[e];
    if (tid < OUT_) scl[tid] = wsp[tid]*catt[n*OUT_+tid];
    __syncthreads();
    if (tid < REL_*V_){
        int r = tid/V_, v = tid%V_;
        float s = 0.f;
        for (int c=0;c<OUT_;++c) s = fmaf(scl[c]*w4l[c*REL_+r], xbl[c*V_+v], s);
        Wl[tid] = s;
    } else if (tid < REL_*V_ + V_){
        int v = tid - REL_*V_;
        float s = 0.f;
        for (int c=0;c<OUT_;++c) s = fmaf(scl[c], xbl[c*V_+v], s);
        Yl[v] = s;
    }
    __syncthreads();
    if (tid < OUT_){
        float s1 = 0.f;
        #pragma unroll
        for (int v=0;v<V_;++v) s1 += xbl[tid*V_+v];
        red[tid] = scl[tid]*b4[tid]*s1;
    }
    __syncthreads();
    if (tid < V_){
        int u = tid;
        float acc = 0.f;
        #pragma unroll
        for (int r=0;r<REL_;++r){
            const float* xr = xml + r*VV_ + u*V_;
            const float* wr = Wl + r*V_;
            #pragma unroll
            for (int v=0;v<V_;++v) acc = fmaf(xr[v], wr[v], acc);
        }
        #pragma unroll
        for (int v=0;v<V_;++v) acc = fmaf(Al[u*V_+v], Yl[v], acc);
        float beta = 0.f;
        for (int c=0;c<OUT_;++c) beta += red[c];
        satt[n*V_+u] = 1.0f/(1.0f+expf(-(bsp[0]+acc+beta)));
    }
}

// Kcomb3: per (n,c): comb[t,w] = sum_u x3[t,u]*M[w,u],
//   M[w,u] = ca*(x1c+A)[w,u] + attc[u,w]*satt[w],
// with x1c/attc reconstructed on the fly from xm/att8 (L2-hot, 40KB/n).
__global__ __launch_bounds__(256) void k_comb3(
    const bf16* __restrict__ x3h,
    const float* __restrict__ att8, const float* __restrict__ xm,
    const float* __restrict__ A,
    const float* __restrict__ watt, const float* __restrict__ batt,
    const float* __restrict__ w4, const float* __restrict__ b4,
    const float* __restrict__ catt, const float* __restrict__ satt,
    bf16* __restrict__ combh)
{
    __shared__ __align__(16) unsigned short x3s[TV_];   // 6.4KB
    __shared__ float Ml[VV_];
    __shared__ float sl[V_];
    __shared__ __align__(16) unsigned short cst[TV_];   // 6.4KB
    int bid = blockIdx.x;   // n*OUT + c
    int n = bid >> 6, c = bid & 63;
    int tid = threadIdx.x;
    for (int e = tid; e < 400; e += 256)
        ((uint4*)x3s)[e] = ((const uint4*)(x3h + (size_t)bid*TV_))[e];
    if (tid < V_) sl[tid] = satt[n*V_+tid];
    float ca = catt[bid];
    float w4r[REL_], war[REL_];
    #pragma unroll
    for (int r=0;r<REL_;++r){ w4r[r] = w4[c*REL_+r]; war[r] = watt[c*REL_+r]; }
    float b4c = b4[c], bac = batt[c];
    const float* xmn = xm  + (size_t)n*REL_*VV_;
    const float* a8n = att8 + (size_t)n*REL_*VV_;
    __syncthreads();
    for (int e = tid; e < VV_; e += 256){
        int w = e/V_, u = e%V_;
        float xv = b4c, av = bac;
        #pragma unroll
        for (int r=0;r<REL_;++r){
            xv = fmaf(w4r[r], xmn[r*VV_ + e], xv);
            av = fmaf(war[r], a8n[r*VV_ + u*V_ + w], av);
        }
        Ml[e] = ca*(xv + A[e]) + av*sl[w];
    }
    __syncthreads();
    int vh = tid & 1, tq = tid >> 1;
    int v0 = vh*13, nv = vh ? 12 : 13;
    float x3r[V_];
    #pragma unroll
    for (int u=0;u<V_;++u) x3r[u] = bfs(x3s[tq*V_+u]);
    for (int i=0;i<nv;++i){
        int v = v0+i;
        float s=0.f;
        #pragma unroll
        for (int u=0;u<V_;++u) s = fmaf(Ml[v*V_+u], x3r[u], s);
        bf16 h = f2b(s);
        cst[tq*V_+v] = *(unsigned short*)&h;
    }
    __syncthreads();
    for (int e = tid; e < 400; e += 256)
        ((uint4*)(combh + (size_t)bid*TV_))[e] = ((const uint4*)cst)[e];
}

// K10f5: R4 structure, c-half split across grid (N*16*2 blocks), NO bounds cap.
// Phase 1: xt tile (recomputed per half, ~2us chip-wide). Phase 2: single
// 32-channel round, stage comb|x3 AFTER phase 1 (clean pattern).
__global__ __launch_bounds__(256) void k10_final5(
    const float* __restrict__ x11f, const float* __restrict__ x22f,
    const bf16* __restrict__ x3h, const bf16* __restrict__ combh,
    const float* __restrict__ beita, float* __restrict__ out)
{
    __shared__ __align__(16) char stg[25600];                // phase1: l11|l22 ; phase2: staging
    __shared__ __align__(16) unsigned short xtl[TT2*V_*28];  // 11.2KB
    int bid = blockIdx.x;              // n*32 + tt*2 + half
    int n = bid >> 5, rem = bid & 31;
    int tt = rem >> 1, half = rem & 1;
    int t0 = tt * TT2, c0 = half*32;
    int tid = threadIdx.x;
    float* l11 = (float*)stg;
    float* l22 = (float*)(stg + 6400);
    for (int e = tid; e < 400; e += 256){
        int r = e / 50, rem2 = e % 50;
        ((float4*)l11)[e] = ((const float4*)(x11f + (size_t)(n*REL_+r)*TV_ + t0*V_))[rem2];
        ((float4*)l22)[e] = ((const float4*)(x22f + (size_t)(n*REL_+r)*TV_ + t0*V_))[rem2];
    }
    __syncthreads();
    for (int e = tid; e < TT2*VV_; e += 256){
        int ti = e / VV_, uv = e % VV_;
        int u = uv / V_, v = uv % V_;
        float s = 0.f;
        #pragma unroll
        for (int r = 0; r < REL_; ++r)
            s = fmaf(l11[r*200 + ti*V_ + u], l22[r*200 + ti*V_ + v], s);
        bf16 h = f2b(tanhf(s * 0.125f));
        xtl[ti*700 + u*28 + v] = *(unsigned short*)&h;
    }
    __syncthreads();   // xtl ready; stg reads done -> safe to overwrite
    for (int e = tid; e < 1600; e += 256){
        int cl = e / 50, w = e % 50;
        size_t base = (size_t)(n*OUT_ + c0 + cl)*TV_ + (size_t)t0*V_;
        uint4 p = (w < 25) ? ((const uint4*)(combh + base))[w]
                           : ((const uint4*)(x3h  + base))[w-25];
        *(uint4*)(stg + cl*800 + (w<25 ? w*16 : 400 + (w-25)*16)) = p;
    }
    __syncthreads();
    float bt = beita[0];
    int c_local = tid >> 3, ti = tid & 7;
    const unsigned short* x3row  = (const unsigned short*)(stg + c_local*800 + 400) + ti*V_;
    const unsigned short* cmbrow = (const unsigned short*)(stg + c_local*800) + ti*V_;
    float acc[V_];
    #pragma unroll
    for (int w=0;w<V_;++w) acc[w]=0.f;
    #pragma unroll
    for (int u=0;u<V_;++u){
        float xa = bfs(x3row[u]);
        const uint* xr = (const uint*)(xtl + ti*700 + u*28);
        #pragma unroll
        for (int q=0;q<12;++q){
            uint p = xr[q];
            acc[2*q]   = fmaf(xa, bfu(p), acc[2*q]);
            acc[2*q+1] = fmaf(xa, bfh(p), acc[2*q+1]);
        }
        acc[24] = fmaf(xa, bfs(((const unsigned short*)xr)[24]), acc[24]);
    }
    #pragma unroll
    for (int w=0;w<V_;++w)
        acc[w] = fmaf(bt, acc[w], bfs(cmbrow[w]));
    __syncthreads();   // all stage reads done before overwrite
    float* orow = (float*)(stg + c_local*800 + ti*100);
    #pragma unroll
    for (int w=0;w<V_;++w) orow[w] = acc[w];
    __syncthreads();
    for (int e = tid; e < 1600; e += 256){
        int cl = e / 50, q = e % 50;
        *(float4*)(out + (size_t)(n*OUT_ + c0 + cl)*TV_ + (size_t)t0*V_ + q*4) =
            *(const float4*)(stg + cl*800 + q*16);
    }
}

extern "C" void kernel_launch(void* const* d_in, const int* in_sizes, int n_in,
                              void* d_out, int out_size, void* d_ws, size_t ws_size,
                              hipStream_t stream)
{
    const float* x    = (const float*)d_in[0];
    const float* A    = (const float*)d_in[1];
    const float* w1   = (const float*)d_in[2];  const float* b1  = (const float*)d_in[3];
    const float* w2   = (const float*)d_in[4];  const float* b2  = (const float*)d_in[5];
    const float* w11  = (const float*)d_in[6];  const float* b11 = (const float*)d_in[7];
    const float* w22  = (const float*)d_in[8];  const float* b22 = (const float*)d_in[9];
    const float* w3   = (const float*)d_in[10]; const float* b3  = (const float*)d_in[11];
    const float* w4   = (const float*)d_in[12]; const float* b4  = (const float*)d_in[13];
    const float* watt = (const float*)d_in[14]; const float* batt= (const float*)d_in[15];
    const float* w5   = (const float*)d_in[16]; const float* b5  = (const float*)d_in[17];
    const float* wc1  = (const float*)d_in[18]; const float* bc1 = (const float*)d_in[19];
    const float* bng  = (const float*)d_in[20]; const float* bnb = (const float*)d_in[21];
    const float* bnm  = (const float*)d_in[22]; const float* bnv = (const float*)d_in[23];
    const float* wc2  = (const float*)d_in[24]; const float* bc2 = (const float*)d_in[25];
    const float* wsp  = (const float*)d_in[26]; const float* bsp = (const float*)d_in[27];
    const float* beita= (const float*)d_in[28];
    const int*  alpha = (const int*)d_in[29];
    float* out = (float*)d_out;

    char* wsb = (char*)d_ws;
    size_t off = 0;
    auto alloc = [&](size_t bytes)->char*{
        char* p = wsb + off;
        off += (bytes + 255) & ~(size_t)255;
        return p;
    };
    float* x1f   = (float*)alloc((size_t)N_*REL_*TV_*4);
    float* x2f   = (float*)alloc((size_t)N_*REL_*TV_*4);
    float* x11f  = (float*)alloc((size_t)N_*REL_*TV_*4);
    float* x22f  = (float*)alloc((size_t)N_*REL_*TV_*4);
    bf16*  x3h   = (bf16*) alloc((size_t)N_*OUT_*TV_*2);
    bf16*  combh = (bf16*) alloc((size_t)N_*OUT_*TV_*2);
    float* att8  = (float*)alloc((size_t)N_*REL_*VV_*4);
    float* xm    = (float*)alloc((size_t)N_*REL_*VV_*4);
    float* x3bar = (float*)alloc((size_t)N_*OUT_*V_*4);
    float* catt  = (float*)alloc((size_t)N_*OUT_*4);
    float* satt  = (float*)alloc((size_t)N_*V_*4);
    float* WTg   = (float*)alloc((size_t)96*C_*4);
    float* Bg    = (float*)alloc((size_t)96*4);
    (void)ws_size; (void)n_in; (void)in_sizes; (void)out_size;

    k0_prep<<<1, 256, 0, stream>>>(w1,b1, w2,b2, w11,b11, w22,b22, w3,b3, WTg, Bg);
    k1_convs<<<N_*50, 256, 0, stream>>>(x, WTg, Bg, x1f, x2f, x11f, x22f, x3h);
    k_x3bar<<<N_*OUT_, 128, 0, stream>>>(x3h, x3bar);
    k3_att8_xm<<<N_*REL_, 256, 0, stream>>>(x1f, x2f, w5, b5, alpha, att8, xm);
    k6_chatt2<<<N_, 256, 0, stream>>>(att8, x3bar, watt, batt,
                                      wc1, bc1, bng, bnb, bnm, bnv, wc2, bc2, catt);
    k8_satt3<<<N_, 256, 0, stream>>>(xm, A, catt, x3bar, w4, b4, wsp, bsp, satt);
    k_comb3<<<N_*OUT_, 256, 0, stream>>>(x3h, att8, xm, A, watt, batt, w4, b4,
                                         catt, satt, combh);
    k10_final5<<<N_*32, 256, 0, stream>>>(x11f, x22f, x3h, combh, beita, out);
}

// Round 11
// 209.218 us; speedup vs baseline: 1.1475x; 1.1475x over previous
//
#include <hip/hip_runtime.h>
#include <hip/hip_bf16.h>
#include <math.h>

#define N_   64
#define C_   64
#define T_   128
#define V_   25
#define OUT_ 64
#define REL_ 8
#define MID_ 32
#define TV_  (T_*V_)   // 3200
#define VV_  (V_*V_)   // 625
#define TT2  8         // t-tile for fused temporal kernel
#define XTP3 40        // xtl row pad in shorts (80B: 16B-aligned rows, conflict-free b128)

typedef __hip_bfloat16 bf16;
typedef unsigned int uint;
__device__ __forceinline__ float b2f(bf16 x){ return __bfloat162float(x); }
__device__ __forceinline__ bf16  f2b(float x){ return __float2bfloat16(x); }
__device__ __forceinline__ float bfu(uint u){ return __uint_as_float(u<<16); }
__device__ __forceinline__ float bfh(uint u){ return __uint_as_float(u&0xffff0000u); }
__device__ __forceinline__ float bfs(unsigned short s){ return __uint_as_float(((uint)s)<<16); }

// fast tanh: clamp + (e^{2x}-1)/(e^{2x}+1); ~7 inst vs libm tanhf ~30.
// abs err ~1e-6, threshold is 1.9e-2.
__device__ __forceinline__ float ftanh(float x){
    float cx = fminf(fmaxf(x, -15.f), 15.f);
    float e  = __expf(2.0f*cx);
    return (e - 1.0f) / (e + 1.0f);
}

// LESSONS (measured, R4-R10):
//  * k10 needs ~156 VGPR (acc[25]). ANY min-waves launch_bounds cap ->
//    scratch spill -> ~1.1GB HBM scratch traffic, 2.5-4x slower (R6/R7/R8).
//  * k10 is VGPR-occupancy-bound (3 waves/SIMD); grid half-split (R10) adds
//    duplicate phase-1 work with zero occupancy gain -> 92->119us. Reverted.
//  * R4 staging structure (inside-round, after phase-1 compute) is clean.
//  * attc/x1c materialization (~614MB traffic) eliminated algebraically (R10).

// K0: one-time transpose of the 5 conv weight matrices into WTg[c][96] (+ biases Bg[96])
__global__ __launch_bounds__(256) void k0_prep(
    const float* __restrict__ w1, const float* __restrict__ b1,
    const float* __restrict__ w2, const float* __restrict__ b2,
    const float* __restrict__ w11, const float* __restrict__ b11,
    const float* __restrict__ w22, const float* __restrict__ b22,
    const float* __restrict__ w3, const float* __restrict__ b3,
    float* __restrict__ WTg, float* __restrict__ Bg)
{
    int tid = threadIdx.x;
    for (int e = tid; e < 96*C_; e += 256){
        int o = e / C_, c = e % C_;
        float w;
        if      (o < 8)  w = w1[o*C_+c];
        else if (o < 16) w = w2[(o-8)*C_+c];
        else if (o < 24) w = w11[(o-16)*C_+c];
        else if (o < 32) w = w22[(o-24)*C_+c];
        else             w = w3[(o-32)*C_+c];
        WTg[c*96 + o] = w;
    }
    if (tid < 96){
        int o = tid; float bb;
        if      (o < 8)  bb = b1[o];
        else if (o < 16) bb = b2[o-8];
        else if (o < 24) bb = b11[o-16];
        else if (o < 32) bb = b22[o-24];
        else             bb = b3[o-32];
        Bg[o] = bb;
    }
}

// K1: all five 1x1 convs. block = (n, 64-wide j tile); thread = 6 o x 4 j micro-tile.
__global__ __launch_bounds__(256) void k1_convs(
    const float* __restrict__ x,
    const float* __restrict__ WTg, const float* __restrict__ Bg,
    float* __restrict__ x1f, float* __restrict__ x2f,
    float* __restrict__ x11f, float* __restrict__ x22f,
    bf16* __restrict__ x3h)
{
    __shared__ __align__(16) float xl[C_*64];    // 16KB
    __shared__ __align__(16) float WTl[C_*96];   // 24KB
    __shared__ float Bl[96];
    int bid = blockIdx.x;
    int n = bid / 50, jt = bid % 50;
    int j0 = jt * 64;
    int tid = threadIdx.x;
    for (int e = tid; e < 1024; e += 256){
        int c = e >> 4, j4 = e & 15;
        ((float4*)xl)[e] = ((const float4*)(x + (size_t)(n*C_+c)*TV_ + j0))[j4];
    }
    for (int e = tid; e < 1536; e += 256)
        ((float4*)WTl)[e] = ((const float4*)WTg)[e];
    if (tid < 96) Bl[tid] = Bg[tid];
    __syncthreads();

    int og = tid >> 4;
    int jg = tid & 15;
    int o0 = og*6, jj = jg*4;
    float acc[6][4];
    #pragma unroll
    for (int i=0;i<6;i++){
        float b = Bl[o0+i];
        #pragma unroll
        for (int q=0;q<4;q++) acc[i][q] = b;
    }
    #pragma unroll 8
    for (int c = 0; c < C_; ++c){
        float4 xv = *(const float4*)&xl[c*64 + jj];
        #pragma unroll
        for (int i=0;i<6;i++){
            float w = WTl[c*96 + o0 + i];
            acc[i][0] = fmaf(w, xv.x, acc[i][0]);
            acc[i][1] = fmaf(w, xv.y, acc[i][1]);
            acc[i][2] = fmaf(w, xv.z, acc[i][2]);
            acc[i][3] = fmaf(w, xv.w, acc[i][3]);
        }
    }
    int pos = j0 + jj;
    #pragma unroll
    for (int i=0;i<6;i++){
        int o = o0 + i;
        float4 v = make_float4(acc[i][0], acc[i][1], acc[i][2], acc[i][3]);
        if      (o < 8)  *(float4*)&x1f [(size_t)(n*REL_+o)     *TV_ + pos] = v;
        else if (o < 16) *(float4*)&x2f [(size_t)(n*REL_+(o-8)) *TV_ + pos] = v;
        else if (o < 24) *(float4*)&x11f[(size_t)(n*REL_+(o-16))*TV_ + pos] = v;
        else if (o < 32) *(float4*)&x22f[(size_t)(n*REL_+(o-24))*TV_ + pos] = v;
        else {
            bf16 h0=f2b(v.x), h1=f2b(v.y), h2=f2b(v.z), h3=f2b(v.w);
            ushort4 pk;
            pk.x = *(unsigned short*)&h0; pk.y = *(unsigned short*)&h1;
            pk.z = *(unsigned short*)&h2; pk.w = *(unsigned short*)&h3;
            *(ushort4*)&x3h[(size_t)(n*OUT_+(o-32))*TV_ + pos] = pk;
        }
    }
}

// Kx3bar: x3bar[n,c,v] = mean_t x3[n,c,t,v]
__global__ __launch_bounds__(128) void k_x3bar(const bf16* __restrict__ x3h,
                                               float* __restrict__ x3bar)
{
    __shared__ float red[128*26];
    int bid = blockIdx.x;   // n*OUT + c
    int t = threadIdx.x;
    const bf16* row = x3h + (size_t)bid*TV_ + t*V_;
    #pragma unroll
    for (int v=0;v<V_;++v) red[t*26+v] = b2f(row[v]);
    __syncthreads();
    for (int s=64; s>0; s>>=1){
        if (t < s){
            #pragma unroll
            for (int v=0;v<V_;++v) red[t*26+v] += red[(t+s)*26+v];
        }
        __syncthreads();
    }
    if (t < V_) x3bar[(size_t)bid*V_+t] = red[t] * (1.0f/T_);
}

// K3: att8 = tanh(x1^T x2 / T);  xm = tanh(w5_0*mean_res + w5_1*max_res + b5)*alpha
__global__ __launch_bounds__(256) void k3_att8_xm(
    const float* __restrict__ x1f, const float* __restrict__ x2f,
    const float* __restrict__ w5, const float* __restrict__ b5,
    const int* __restrict__ alpha,
    float* __restrict__ att8, float* __restrict__ xm)
{
    __shared__ __align__(16) float l1[TV_], l2[TV_];
    __shared__ float mu1l[V_], mu2l[V_], m1l[V_], m2l[V_];
    int bid = blockIdx.x;      // n*REL + r
    int tid = threadIdx.x;
    int r = bid % REL_;
    for (int e = tid; e < 800; e += 256){
        ((float4*)l1)[e] = ((const float4*)(x1f + (size_t)bid*TV_))[e];
        ((float4*)l2)[e] = ((const float4*)(x2f + (size_t)bid*TV_))[e];
    }
    __syncthreads();
    if (tid < 50){
        int v = tid % V_;
        const float* L = (tid < V_) ? l1 : l2;
        float s=0.f, mm=-1e30f;
        for (int t=0;t<T_;++t){
            float a = L[t*V_+v];
            s += a; mm = fmaxf(mm, a);
        }
        if (tid < V_){ mu1l[v]=s*(1.0f/T_); m1l[v]=mm; }
        else         { mu2l[v]=s*(1.0f/T_); m2l[v]=mm; }
    }
    __syncthreads();
    float w50=w5[r*2+0], w51=w5[r*2+1], b5r=b5[r];
    float af = (float)alpha[0];
    for (int idx=tid; idx<VV_; idx+=256){
        int u = idx/V_, v = idx%V_;
        float s=0.f;
        for (int t=0;t<T_;++t) s = fmaf(l1[t*V_+u], l2[t*V_+v], s);
        att8[(size_t)bid*VV_+idx] = ftanh(s*(1.0f/T_));
        float mr = mu1l[u]-mu2l[v];
        float xr = m1l[u]-m2l[v];
        xm[(size_t)bid*VV_+idx] = ftanh(fmaf(w50,mr,fmaf(w51,xr,b5r))) * af;
    }
}

// K6v2: g[n,c] = (1/V)(sum_r watt[c,r]*<x3bar[c], rowsum(att8_r)> + V*batt[c]*sum(x3bar[c]))
//        then channel attention chain. No attc materialization.
__global__ __launch_bounds__(256) void k6_chatt2(
    const float* __restrict__ att8, const float* __restrict__ x3bar,
    const float* __restrict__ watt, const float* __restrict__ batt,
    const float* __restrict__ wc1, const float* __restrict__ bc1,
    const float* __restrict__ bng, const float* __restrict__ bnb,
    const float* __restrict__ bnm, const float* __restrict__ bnv,
    const float* __restrict__ wc2, const float* __restrict__ bc2,
    float* __restrict__ catt)
{
    __shared__ float rs8[REL_*V_];
    __shared__ float gl[OUT_];
    __shared__ float hl[MID_];
    int n = blockIdx.x, tid = threadIdx.x;
    if (tid < REL_*V_){
        int r = tid / V_, u = tid % V_;
        const float* p = att8 + (size_t)(n*REL_+r)*VV_ + u*V_;
        float s = 0.f;
        #pragma unroll
        for (int v=0;v<V_;++v) s += p[v];
        rs8[tid] = s;
    }
    __syncthreads();
    if (tid < OUT_){
        int c = tid;
        const float* xb = x3bar + (size_t)(n*OUT_+c)*V_;
        float xbr[V_], sb = 0.f;
        #pragma unroll
        for (int u=0;u<V_;++u){ xbr[u]=xb[u]; sb += xbr[u]; }
        float s = 0.f;
        #pragma unroll
        for (int r=0;r<REL_;++r){
            float d = 0.f;
            #pragma unroll
            for (int u=0;u<V_;++u) d = fmaf(xbr[u], rs8[r*V_+u], d);
            s = fmaf(watt[c*REL_+r], d, s);
        }
        gl[c] = (s + (float)V_*batt[c]*sb) * (1.0f/(float)V_);
    }
    __syncthreads();
    if (tid < MID_){
        float h = bc1[tid];
        for (int c=0;c<OUT_;++c) h = fmaf(wc1[tid*OUT_+c], gl[c], h);
        h = (h - bnm[tid]) * bng[tid] * rsqrtf(bnv[tid] + 1e-5f) + bnb[tid];
        h = 0.5f*h*(1.0f+erff(h*0.70710678118654752f));
        hl[tid]=h;
    }
    __syncthreads();
    if (tid < OUT_){
        float s = bc2[tid];
        for (int m=0;m<MID_;++m) s = fmaf(wc2[tid*MID_+m], hl[m], s);
        catt[n*OUT_+tid] = 1.0f/(1.0f+expf(-s));
    }
}

// K8v3: s_att via c-sum pushed inward (no x1c read).
__global__ __launch_bounds__(256) void k8_satt3(
    const float* __restrict__ xm, const float* __restrict__ A,
    const float* __restrict__ catt, const float* __restrict__ x3bar,
    const float* __restrict__ w4, const float* __restrict__ b4,
    const float* __restrict__ wsp, const float* __restrict__ bsp,
    float* __restrict__ satt)
{
    __shared__ __align__(16) float xml[REL_*VV_];  // 20KB
    __shared__ __align__(16) float xbl[OUT_*V_];   // 6.4KB
    __shared__ float Al[VV_];
    __shared__ float w4l[OUT_*REL_];
    __shared__ float scl[OUT_];
    __shared__ float Wl[REL_*V_];
    __shared__ float Yl[V_];
    __shared__ float red[OUT_];
    int n = blockIdx.x, tid = threadIdx.x;
    for (int e=tid; e<1250; e+=256)
        ((float4*)xml)[e] = ((const float4*)(xm + (size_t)n*REL_*VV_))[e];
    for (int e=tid; e<400; e+=256)
        ((float4*)xbl)[e] = ((const float4*)(x3bar + (size_t)n*OUT_*V_))[e];
    for (int e=tid; e<VV_; e+=256) Al[e] = A[e];
    for (int e=tid; e<OUT_*REL_; e+=256) w4l[e] = w4[e];
    if (tid < OUT_) scl[tid] = wsp[tid]*catt[n*OUT_+tid];
    __syncthreads();
    if (tid < REL_*V_){
        int r = tid/V_, v = tid%V_;
        float s = 0.f;
        for (int c=0;c<OUT_;++c) s = fmaf(scl[c]*w4l[c*REL_+r], xbl[c*V_+v], s);
        Wl[tid] = s;
    } else if (tid < REL_*V_ + V_){
        int v = tid - REL_*V_;
        float s = 0.f;
        for (int c=0;c<OUT_;++c) s = fmaf(scl[c], xbl[c*V_+v], s);
        Yl[v] = s;
    }
    __syncthreads();
    if (tid < OUT_){
        float s1 = 0.f;
        #pragma unroll
        for (int v=0;v<V_;++v) s1 += xbl[tid*V_+v];
        red[tid] = scl[tid]*b4[tid]*s1;
    }
    __syncthreads();
    if (tid < V_){
        int u = tid;
        float acc = 0.f;
        #pragma unroll
        for (int r=0;r<REL_;++r){
            const float* xr = xml + r*VV_ + u*V_;
            const float* wr = Wl + r*V_;
            #pragma unroll
            for (int v=0;v<V_;++v) acc = fmaf(xr[v], wr[v], acc);
        }
        #pragma unroll
        for (int v=0;v<V_;++v) acc = fmaf(Al[u*V_+v], Yl[v], acc);
        float beta = 0.f;
        for (int c=0;c<OUT_;++c) beta += red[c];
        satt[n*V_+u] = 1.0f/(1.0f+expf(-(bsp[0]+acc+beta)));
    }
}

// Kcomb3: per (n,c): comb[t,w] = sum_u x3[t,u]*M[w,u],
//   M built on the fly from xm/att8 (L2-hot).
__global__ __launch_bounds__(256) void k_comb3(
    const bf16* __restrict__ x3h,
    const float* __restrict__ att8, const float* __restrict__ xm,
    const float* __restrict__ A,
    const float* __restrict__ watt, const float* __restrict__ batt,
    const float* __restrict__ w4, const float* __restrict__ b4,
    const float* __restrict__ catt, const float* __restrict__ satt,
    bf16* __restrict__ combh)
{
    __shared__ __align__(16) unsigned short x3s[TV_];   // 6.4KB
    __shared__ float Ml[VV_];
    __shared__ float sl[V_];
    __shared__ __align__(16) unsigned short cst[TV_];   // 6.4KB
    int bid = blockIdx.x;   // n*OUT + c
    int n = bid >> 6, c = bid & 63;
    int tid = threadIdx.x;
    for (int e = tid; e < 400; e += 256)
        ((uint4*)x3s)[e] = ((const uint4*)(x3h + (size_t)bid*TV_))[e];
    if (tid < V_) sl[tid] = satt[n*V_+tid];
    float ca = catt[bid];
    float w4r[REL_], war[REL_];
    #pragma unroll
    for (int r=0;r<REL_;++r){ w4r[r] = w4[c*REL_+r]; war[r] = watt[c*REL_+r]; }
    float b4c = b4[c], bac = batt[c];
    const float* xmn = xm  + (size_t)n*REL_*VV_;
    const float* a8n = att8 + (size_t)n*REL_*VV_;
    __syncthreads();
    for (int e = tid; e < VV_; e += 256){
        int w = e/V_, u = e%V_;
        float xv = b4c, av = bac;
        #pragma unroll
        for (int r=0;r<REL_;++r){
            xv = fmaf(w4r[r], xmn[r*VV_ + e], xv);
            av = fmaf(war[r], a8n[r*VV_ + u*V_ + w], av);
        }
        Ml[e] = ca*(xv + A[e]) + av*sl[w];
    }
    __syncthreads();
    int vh = tid & 1, tq = tid >> 1;
    int v0 = vh*13, nv = vh ? 12 : 13;
    float x3r[V_];
    #pragma unroll
    for (int u=0;u<V_;++u) x3r[u] = bfs(x3s[tq*V_+u]);
    for (int i=0;i<nv;++i){
        int v = v0+i;
        float s=0.f;
        #pragma unroll
        for (int u=0;u<V_;++u) s = fmaf(Ml[v*V_+u], x3r[u], s);
        bf16 h = f2b(s);
        cst[tq*V_+v] = *(unsigned short*)&h;
    }
    __syncthreads();
    for (int e = tid; e < 400; e += 256)
        ((uint4*)(combh + (size_t)bid*TV_))[e] = ((const uint4*)cst)[e];
}

// K10f6: R4 two-round structure (grid N*16, measured clean) + fast tanh +
// 16B-aligned xtl rows (XTP3=40 shorts) so phase-2 row reads become b128.
// NO min-waves bound (acc[25] must stay in registers).
__global__ __launch_bounds__(256) void k10_final6(
    const float* __restrict__ x11f, const float* __restrict__ x22f,
    const bf16* __restrict__ x3h, const bf16* __restrict__ combh,
    const float* __restrict__ beita, float* __restrict__ out)
{
    __shared__ __align__(16) char stg[25600];                 // phase1: l11|l22 ; phase2: staging
    __shared__ __align__(16) unsigned short xtl[TT2*V_*XTP3]; // 16KB
    int bid = blockIdx.x;              // n*16 + tt
    int n = bid >> 4, tt = bid & 15;
    int t0 = tt * TT2;
    int tid = threadIdx.x;
    float* l11 = (float*)stg;          // [8][8][25]
    float* l22 = (float*)(stg + 6400);
    for (int e = tid; e < 400; e += 256){
        int r = e / 50, rem = e % 50;
        ((float4*)l11)[e] = ((const float4*)(x11f + (size_t)(n*REL_+r)*TV_ + t0*V_))[rem];
        ((float4*)l22)[e] = ((const float4*)(x22f + (size_t)(n*REL_+r)*TV_ + t0*V_))[rem];
    }
    __syncthreads();
    for (int e = tid; e < TT2*VV_; e += 256){
        int ti = e / VV_, uv = e % VV_;
        int u = uv / V_, v = uv % V_;
        float s = 0.f;
        #pragma unroll
        for (int r = 0; r < REL_; ++r)
            s = fmaf(l11[r*200 + ti*V_ + u], l22[r*200 + ti*V_ + v], s);
        bf16 h = f2b(ftanh(s * 0.125f));
        xtl[ti*(V_*XTP3) + u*XTP3 + v] = *(unsigned short*)&h;
    }
    float bt = beita[0];
    int c_local = tid >> 3, ti = tid & 7;
    for (int cr = 0; cr < 2; ++cr){
        int c0 = cr*32;
        __syncthreads();   // xtl ready (cr=0) / prev store done (cr=1)
        for (int e = tid; e < 1600; e += 256){
            int cl = e / 50, w = e % 50;
            size_t base = (size_t)(n*OUT_ + c0 + cl)*TV_ + (size_t)t0*V_;
            uint4 p = (w < 25) ? ((const uint4*)(combh + base))[w]
                               : ((const uint4*)(x3h  + base))[w-25];
            *(uint4*)(stg + cl*800 + (w<25 ? w*16 : 400 + (w-25)*16)) = p;
        }
        __syncthreads();
        const unsigned short* x3row  = (const unsigned short*)(stg + c_local*800 + 400) + ti*V_;
        const unsigned short* cmbrow = (const unsigned short*)(stg + c_local*800) + ti*V_;
        float acc[V_];
        #pragma unroll
        for (int w=0;w<V_;++w) acc[w]=0.f;
        #pragma unroll
        for (int u=0;u<V_;++u){
            float xa = bfs(x3row[u]);
            const uint* xr = (const uint*)(xtl + ti*(V_*XTP3) + u*XTP3); // 16B-aligned
            #pragma unroll
            for (int q=0;q<12;++q){
                uint p = xr[q];
                acc[2*q]   = fmaf(xa, bfu(p), acc[2*q]);
                acc[2*q+1] = fmaf(xa, bfh(p), acc[2*q+1]);
            }
            acc[24] = fmaf(xa, bfs(((const unsigned short*)xr)[24]), acc[24]);
        }
        #pragma unroll
        for (int w=0;w<V_;++w)
            acc[w] = fmaf(bt, acc[w], bfs(cmbrow[w]));
        __syncthreads();   // all stage reads done before overwrite
        float* orow = (float*)(stg + c_local*800 + ti*100);
        #pragma unroll
        for (int w=0;w<V_;++w) orow[w] = acc[w];
        __syncthreads();
        for (int e = tid; e < 1600; e += 256){
            int cl = e / 50, q = e % 50;
            *(float4*)(out + (size_t)(n*OUT_ + c0 + cl)*TV_ + (size_t)t0*V_ + q*4) =
                *(const float4*)(stg + cl*800 + q*16);
        }
    }
}

extern "C" void kernel_launch(void* const* d_in, const int* in_sizes, int n_in,
                              void* d_out, int out_size, void* d_ws, size_t ws_size,
                              hipStream_t stream)
{
    const float* x    = (const float*)d_in[0];
    const float* A    = (const float*)d_in[1];
    const float* w1   = (const float*)d_in[2];  const float* b1  = (const float*)d_in[3];
    const float* w2   = (const float*)d_in[4];  const float* b2  = (const float*)d_in[5];
    const float* w11  = (const float*)d_in[6];  const float* b11 = (const float*)d_in[7];
    const float* w22  = (const float*)d_in[8];  const float* b22 = (const float*)d_in[9];
    const float* w3   = (const float*)d_in[10]; const float* b3  = (const float*)d_in[11];
    const float* w4   = (const float*)d_in[12]; const float* b4  = (const float*)d_in[13];
    const float* watt = (const float*)d_in[14]; const float* batt= (const float*)d_in[15];
    const float* w5   = (const float*)d_in[16]; const float* b5  = (const float*)d_in[17];
    const float* wc1  = (const float*)d_in[18]; const float* bc1 = (const float*)d_in[19];
    const float* bng  = (const float*)d_in[20]; const float* bnb = (const float*)d_in[21];
    const float* bnm  = (const float*)d_in[22]; const float* bnv = (const float*)d_in[23];
    const float* wc2  = (const float*)d_in[24]; const float* bc2 = (const float*)d_in[25];
    const float* wsp  = (const float*)d_in[26]; const float* bsp = (const float*)d_in[27];
    const float* beita= (const float*)d_in[28];
    const int*  alpha = (const int*)d_in[29];
    float* out = (float*)d_out;

    char* wsb = (char*)d_ws;
    size_t off = 0;
    auto alloc = [&](size_t bytes)->char*{
        char* p = wsb + off;
        off += (bytes + 255) & ~(size_t)255;
        return p;
    };
    float* x1f   = (float*)alloc((size_t)N_*REL_*TV_*4);
    float* x2f   = (float*)alloc((size_t)N_*REL_*TV_*4);
    float* x11f  = (float*)alloc((size_t)N_*REL_*TV_*4);
    float* x22f  = (float*)alloc((size_t)N_*REL_*TV_*4);
    bf16*  x3h   = (bf16*) alloc((size_t)N_*OUT_*TV_*2);
    bf16*  combh = (bf16*) alloc((size_t)N_*OUT_*TV_*2);
    float* att8  = (float*)alloc((size_t)N_*REL_*VV_*4);
    float* xm    = (float*)alloc((size_t)N_*REL_*VV_*4);
    float* x3bar = (float*)alloc((size_t)N_*OUT_*V_*4);
    float* catt  = (float*)alloc((size_t)N_*OUT_*4);
    float* satt  = (float*)alloc((size_t)N_*V_*4);
    float* WTg   = (float*)alloc((size_t)96*C_*4);
    float* Bg    = (float*)alloc((size_t)96*4);
    (void)ws_size; (void)n_in; (void)in_sizes; (void)out_size;

    k0_prep<<<1, 256, 0, stream>>>(w1,b1, w2,b2, w11,b11, w22,b22, w3,b3, WTg, Bg);
    k1_convs<<<N_*50, 256, 0, stream>>>(x, WTg, Bg, x1f, x2f, x11f, x22f, x3h);
    k_x3bar<<<N_*OUT_, 128, 0, stream>>>(x3h, x3bar);
    k3_att8_xm<<<N_*REL_, 256, 0, stream>>>(x1f, x2f, w5, b5, alpha, att8, xm);
    k6_chatt2<<<N_, 256, 0, stream>>>(att8, x3bar, watt, batt,
                                      wc1, bc1, bng, bnb, bnm, bnv, wc2, bc2, catt);
    k8_satt3<<<N_, 256, 0, stream>>>(xm, A, catt, x3bar, w4, b4, wsp, bsp, satt);
    k_comb3<<<N_*OUT_, 256, 0, stream>>>(x3h, att8, xm, A, watt, batt, w4, b4,
                                         catt, satt, combh);
    k10_final6<<<N_*16, 256, 0, stream>>>(x11f, x22f, x3h, combh, beita, out);
}

// Round 12
// 171.467 us; speedup vs baseline: 1.4002x; 1.2202x over previous
//
#include <hip/hip_runtime.h>
#include <hip/hip_bf16.h>
#include <math.h>

#define N_   64
#define C_   64
#define T_   128
#define V_   25
#define OUT_ 64
#define REL_ 8
#define MID_ 32
#define TV_  (T_*V_)   // 3200
#define VV_  (V_*V_)   // 625
#define TT2  8         // t-tile for fused temporal kernel
#define XTP3 40        // xtl row pad in shorts (80B: 16B-aligned rows)

typedef __hip_bfloat16 bf16;
typedef unsigned int uint;
__device__ __forceinline__ float b2f(bf16 x){ return __bfloat162float(x); }
__device__ __forceinline__ bf16  f2b(float x){ return __float2bfloat16(x); }
__device__ __forceinline__ float bfu(uint u){ return __uint_as_float(u<<16); }
__device__ __forceinline__ float bfh(uint u){ return __uint_as_float(u&0xffff0000u); }
__device__ __forceinline__ float bfs(unsigned short s){ return __uint_as_float(((uint)s)<<16); }

// fast tanh: clamp + (e^{2x}-1)/(e^{2x}+1); abs err ~1e-6, threshold 1.9e-2.
__device__ __forceinline__ float ftanh(float x){
    float cx = fminf(fmaxf(x, -15.f), 15.f);
    float e  = __expf(2.0f*cx);
    return (e - 1.0f) / (e + 1.0f);
}

// LESSONS (measured, R4-R11):
//  * k10's acc[] size sets VGPR (acc[25] -> 156 VGPR -> 3 waves/SIMD).
//    launch_bounds caps -> spill -> 1.1GB scratch traffic (R6/R7/R8). Caps banned.
//    Grid-split w/o VGPR reduction: no occupancy gain, +dup work (R10, 92->119).
//    => This round: HALVE acc via wave-uniform v-split (acc[13], 512-thr blocks).
//  * R4 staging structure (inside-round, after phase-1 compute) is clean.
//  * attc/x1c materialization (~614MB traffic) eliminated algebraically (R10).

// K0: one-time transpose of the 5 conv weight matrices into WTg[c][96] (+ biases Bg[96])
__global__ __launch_bounds__(256) void k0_prep(
    const float* __restrict__ w1, const float* __restrict__ b1,
    const float* __restrict__ w2, const float* __restrict__ b2,
    const float* __restrict__ w11, const float* __restrict__ b11,
    const float* __restrict__ w22, const float* __restrict__ b22,
    const float* __restrict__ w3, const float* __restrict__ b3,
    float* __restrict__ WTg, float* __restrict__ Bg)
{
    int tid = threadIdx.x;
    for (int e = tid; e < 96*C_; e += 256){
        int o = e / C_, c = e % C_;
        float w;
        if      (o < 8)  w = w1[o*C_+c];
        else if (o < 16) w = w2[(o-8)*C_+c];
        else if (o < 24) w = w11[(o-16)*C_+c];
        else if (o < 32) w = w22[(o-24)*C_+c];
        else             w = w3[(o-32)*C_+c];
        WTg[c*96 + o] = w;
    }
    if (tid < 96){
        int o = tid; float bb;
        if      (o < 8)  bb = b1[o];
        else if (o < 16) bb = b2[o-8];
        else if (o < 24) bb = b11[o-16];
        else if (o < 32) bb = b22[o-24];
        else             bb = b3[o-32];
        Bg[o] = bb;
    }
}

// K1: all five 1x1 convs. block = (n, 64-wide j tile); thread = 6 o x 4 j micro-tile.
__global__ __launch_bounds__(256) void k1_convs(
    const float* __restrict__ x,
    const float* __restrict__ WTg, const float* __restrict__ Bg,
    float* __restrict__ x1f, float* __restrict__ x2f,
    float* __restrict__ x11f, float* __restrict__ x22f,
    bf16* __restrict__ x3h)
{
    __shared__ __align__(16) float xl[C_*64];    // 16KB
    __shared__ __align__(16) float WTl[C_*96];   // 24KB
    __shared__ float Bl[96];
    int bid = blockIdx.x;
    int n = bid / 50, jt = bid % 50;
    int j0 = jt * 64;
    int tid = threadIdx.x;
    for (int e = tid; e < 1024; e += 256){
        int c = e >> 4, j4 = e & 15;
        ((float4*)xl)[e] = ((const float4*)(x + (size_t)(n*C_+c)*TV_ + j0))[j4];
    }
    for (int e = tid; e < 1536; e += 256)
        ((float4*)WTl)[e] = ((const float4*)WTg)[e];
    if (tid < 96) Bl[tid] = Bg[tid];
    __syncthreads();

    int og = tid >> 4;
    int jg = tid & 15;
    int o0 = og*6, jj = jg*4;
    float acc[6][4];
    #pragma unroll
    for (int i=0;i<6;i++){
        float b = Bl[o0+i];
        #pragma unroll
        for (int q=0;q<4;q++) acc[i][q] = b;
    }
    #pragma unroll 8
    for (int c = 0; c < C_; ++c){
        float4 xv = *(const float4*)&xl[c*64 + jj];
        #pragma unroll
        for (int i=0;i<6;i++){
            float w = WTl[c*96 + o0 + i];
            acc[i][0] = fmaf(w, xv.x, acc[i][0]);
            acc[i][1] = fmaf(w, xv.y, acc[i][1]);
            acc[i][2] = fmaf(w, xv.z, acc[i][2]);
            acc[i][3] = fmaf(w, xv.w, acc[i][3]);
        }
    }
    int pos = j0 + jj;
    #pragma unroll
    for (int i=0;i<6;i++){
        int o = o0 + i;
        float4 v = make_float4(acc[i][0], acc[i][1], acc[i][2], acc[i][3]);
        if      (o < 8)  *(float4*)&x1f [(size_t)(n*REL_+o)     *TV_ + pos] = v;
        else if (o < 16) *(float4*)&x2f [(size_t)(n*REL_+(o-8)) *TV_ + pos] = v;
        else if (o < 24) *(float4*)&x11f[(size_t)(n*REL_+(o-16))*TV_ + pos] = v;
        else if (o < 32) *(float4*)&x22f[(size_t)(n*REL_+(o-24))*TV_ + pos] = v;
        else {
            bf16 h0=f2b(v.x), h1=f2b(v.y), h2=f2b(v.z), h3=f2b(v.w);
            ushort4 pk;
            pk.x = *(unsigned short*)&h0; pk.y = *(unsigned short*)&h1;
            pk.z = *(unsigned short*)&h2; pk.w = *(unsigned short*)&h3;
            *(ushort4*)&x3h[(size_t)(n*OUT_+(o-32))*TV_ + pos] = pk;
        }
    }
}

// Kx3bar: x3bar[n,c,v] = mean_t x3[n,c,t,v]
__global__ __launch_bounds__(128) void k_x3bar(const bf16* __restrict__ x3h,
                                               float* __restrict__ x3bar)
{
    __shared__ float red[128*26];
    int bid = blockIdx.x;   // n*OUT + c
    int t = threadIdx.x;
    const bf16* row = x3h + (size_t)bid*TV_ + t*V_;
    #pragma unroll
    for (int v=0;v<V_;++v) red[t*26+v] = b2f(row[v]);
    __syncthreads();
    for (int s=64; s>0; s>>=1){
        if (t < s){
            #pragma unroll
            for (int v=0;v<V_;++v) red[t*26+v] += red[(t+s)*26+v];
        }
        __syncthreads();
    }
    if (t < V_) x3bar[(size_t)bid*V_+t] = red[t] * (1.0f/T_);
}

// K3: att8 = tanh(x1^T x2 / T);  xm = tanh(w5_0*mean_res + w5_1*max_res + b5)*alpha
__global__ __launch_bounds__(256) void k3_att8_xm(
    const float* __restrict__ x1f, const float* __restrict__ x2f,
    const float* __restrict__ w5, const float* __restrict__ b5,
    const int* __restrict__ alpha,
    float* __restrict__ att8, float* __restrict__ xm)
{
    __shared__ __align__(16) float l1[TV_], l2[TV_];
    __shared__ float mu1l[V_], mu2l[V_], m1l[V_], m2l[V_];
    int bid = blockIdx.x;      // n*REL + r
    int tid = threadIdx.x;
    int r = bid % REL_;
    for (int e = tid; e < 800; e += 256){
        ((float4*)l1)[e] = ((const float4*)(x1f + (size_t)bid*TV_))[e];
        ((float4*)l2)[e] = ((const float4*)(x2f + (size_t)bid*TV_))[e];
    }
    __syncthreads();
    if (tid < 50){
        int v = tid % V_;
        const float* L = (tid < V_) ? l1 : l2;
        float s=0.f, mm=-1e30f;
        for (int t=0;t<T_;++t){
            float a = L[t*V_+v];
            s += a; mm = fmaxf(mm, a);
        }
        if (tid < V_){ mu1l[v]=s*(1.0f/T_); m1l[v]=mm; }
        else         { mu2l[v]=s*(1.0f/T_); m2l[v]=mm; }
    }
    __syncthreads();
    float w50=w5[r*2+0], w51=w5[r*2+1], b5r=b5[r];
    float af = (float)alpha[0];
    for (int idx=tid; idx<VV_; idx+=256){
        int u = idx/V_, v = idx%V_;
        float s=0.f;
        for (int t=0;t<T_;++t) s = fmaf(l1[t*V_+u], l2[t*V_+v], s);
        att8[(size_t)bid*VV_+idx] = ftanh(s*(1.0f/T_));
        float mr = mu1l[u]-mu2l[v];
        float xr = m1l[u]-m2l[v];
        xm[(size_t)bid*VV_+idx] = ftanh(fmaf(w50,mr,fmaf(w51,xr,b5r))) * af;
    }
}

// K6v2: channel attention; no attc materialization.
__global__ __launch_bounds__(256) void k6_chatt2(
    const float* __restrict__ att8, const float* __restrict__ x3bar,
    const float* __restrict__ watt, const float* __restrict__ batt,
    const float* __restrict__ wc1, const float* __restrict__ bc1,
    const float* __restrict__ bng, const float* __restrict__ bnb,
    const float* __restrict__ bnm, const float* __restrict__ bnv,
    const float* __restrict__ wc2, const float* __restrict__ bc2,
    float* __restrict__ catt)
{
    __shared__ float rs8[REL_*V_];
    __shared__ float gl[OUT_];
    __shared__ float hl[MID_];
    int n = blockIdx.x, tid = threadIdx.x;
    if (tid < REL_*V_){
        int r = tid / V_, u = tid % V_;
        const float* p = att8 + (size_t)(n*REL_+r)*VV_ + u*V_;
        float s = 0.f;
        #pragma unroll
        for (int v=0;v<V_;++v) s += p[v];
        rs8[tid] = s;
    }
    __syncthreads();
    if (tid < OUT_){
        int c = tid;
        const float* xb = x3bar + (size_t)(n*OUT_+c)*V_;
        float xbr[V_], sb = 0.f;
        #pragma unroll
        for (int u=0;u<V_;++u){ xbr[u]=xb[u]; sb += xbr[u]; }
        float s = 0.f;
        #pragma unroll
        for (int r=0;r<REL_;++r){
            float d = 0.f;
            #pragma unroll
            for (int u=0;u<V_;++u) d = fmaf(xbr[u], rs8[r*V_+u], d);
            s = fmaf(watt[c*REL_+r], d, s);
        }
        gl[c] = (s + (float)V_*batt[c]*sb) * (1.0f/(float)V_);
    }
    __syncthreads();
    if (tid < MID_){
        float h = bc1[tid];
        for (int c=0;c<OUT_;++c) h = fmaf(wc1[tid*OUT_+c], gl[c], h);
        h = (h - bnm[tid]) * bng[tid] * rsqrtf(bnv[tid] + 1e-5f) + bnb[tid];
        h = 0.5f*h*(1.0f+erff(h*0.70710678118654752f));
        hl[tid]=h;
    }
    __syncthreads();
    if (tid < OUT_){
        float s = bc2[tid];
        for (int m=0;m<MID_;++m) s = fmaf(wc2[tid*MID_+m], hl[m], s);
        catt[n*OUT_+tid] = 1.0f/(1.0f+expf(-s));
    }
}

// K8v3: s_att via c-sum pushed inward (no x1c read).
__global__ __launch_bounds__(256) void k8_satt3(
    const float* __restrict__ xm, const float* __restrict__ A,
    const float* __restrict__ catt, const float* __restrict__ x3bar,
    const float* __restrict__ w4, const float* __restrict__ b4,
    const float* __restrict__ wsp, const float* __restrict__ bsp,
    float* __restrict__ satt)
{
    __shared__ __align__(16) float xml[REL_*VV_];  // 20KB
    __shared__ __align__(16) float xbl[OUT_*V_];   // 6.4KB
    __shared__ float Al[VV_];
    __shared__ float w4l[OUT_*REL_];
    __shared__ float scl[OUT_];
    __shared__ float Wl[REL_*V_];
    __shared__ float Yl[V_];
    __shared__ float red[OUT_];
    int n = blockIdx.x, tid = threadIdx.x;
    for (int e=tid; e<1250; e+=256)
        ((float4*)xml)[e] = ((const float4*)(xm + (size_t)n*REL_*VV_))[e];
    for (int e=tid; e<400; e+=256)
        ((float4*)xbl)[e] = ((const float4*)(x3bar + (size_t)n*OUT_*V_))[e];
    for (int e=tid; e<VV_; e+=256) Al[e] = A[e];
    for (int e=tid; e<OUT_*REL_; e+=256) w4l[e] = w4[e];
    if (tid < OUT_) scl[tid] = wsp[tid]*catt[n*OUT_+tid];
    __syncthreads();
    if (tid < REL_*V_){
        int r = tid/V_, v = tid%V_;
        float s = 0.f;
        for (int c=0;c<OUT_;++c) s = fmaf(scl[c]*w4l[c*REL_+r], xbl[c*V_+v], s);
        Wl[tid] = s;
    } else if (tid < REL_*V_ + V_){
        int v = tid - REL_*V_;
        float s = 0.f;
        for (int c=0;c<OUT_;++c) s = fmaf(scl[c], xbl[c*V_+v], s);
        Yl[v] = s;
    }
    __syncthreads();
    if (tid < OUT_){
        float s1 = 0.f;
        #pragma unroll
        for (int v=0;v<V_;++v) s1 += xbl[tid*V_+v];
        red[tid] = scl[tid]*b4[tid]*s1;
    }
    __syncthreads();
    if (tid < V_){
        int u = tid;
        float acc = 0.f;
        #pragma unroll
        for (int r=0;r<REL_;++r){
            const float* xr = xml + r*VV_ + u*V_;
            const float* wr = Wl + r*V_;
            #pragma unroll
            for (int v=0;v<V_;++v) acc = fmaf(xr[v], wr[v], acc);
        }
        #pragma unroll
        for (int v=0;v<V_;++v) acc = fmaf(Al[u*V_+v], Yl[v], acc);
        float beta = 0.f;
        for (int c=0;c<OUT_;++c) beta += red[c];
        satt[n*V_+u] = 1.0f/(1.0f+expf(-(bsp[0]+acc+beta)));
    }
}

// Kcomb3: per (n,c): comb[t,w] = sum_u x3[t,u]*M[w,u], M built on the fly.
__global__ __launch_bounds__(256) void k_comb3(
    const bf16* __restrict__ x3h,
    const float* __restrict__ att8, const float* __restrict__ xm,
    const float* __restrict__ A,
    const float* __restrict__ watt, const float* __restrict__ batt,
    const float* __restrict__ w4, const float* __restrict__ b4,
    const float* __restrict__ catt, const float* __restrict__ satt,
    bf16* __restrict__ combh)
{
    __shared__ __align__(16) unsigned short x3s[TV_];   // 6.4KB
    __shared__ float Ml[VV_];
    __shared__ float sl[V_];
    __shared__ __align__(16) unsigned short cst[TV_];   // 6.4KB
    int bid = blockIdx.x;   // n*OUT + c
    int n = bid >> 6, c = bid & 63;
    int tid = threadIdx.x;
    for (int e = tid; e < 400; e += 256)
        ((uint4*)x3s)[e] = ((const uint4*)(x3h + (size_t)bid*TV_))[e];
    if (tid < V_) sl[tid] = satt[n*V_+tid];
    float ca = catt[bid];
    float w4r[REL_], war[REL_];
    #pragma unroll
    for (int r=0;r<REL_;++r){ w4r[r] = w4[c*REL_+r]; war[r] = watt[c*REL_+r]; }
    float b4c = b4[c], bac = batt[c];
    const float* xmn = xm  + (size_t)n*REL_*VV_;
    const float* a8n = att8 + (size_t)n*REL_*VV_;
    __syncthreads();
    for (int e = tid; e < VV_; e += 256){
        int w = e/V_, u = e%V_;
        float xv = b4c, av = bac;
        #pragma unroll
        for (int r=0;r<REL_;++r){
            xv = fmaf(w4r[r], xmn[r*VV_ + e], xv);
            av = fmaf(war[r], a8n[r*VV_ + u*V_ + w], av);
        }
        Ml[e] = ca*(xv + A[e]) + av*sl[w];
    }
    __syncthreads();
    int vh = tid & 1, tq = tid >> 1;
    int v0 = vh*13, nv = vh ? 12 : 13;
    float x3r[V_];
    #pragma unroll
    for (int u=0;u<V_;++u) x3r[u] = bfs(x3s[tq*V_+u]);
    for (int i=0;i<nv;++i){
        int v = v0+i;
        float s=0.f;
        #pragma unroll
        for (int u=0;u<V_;++u) s = fmaf(Ml[v*V_+u], x3r[u], s);
        bf16 h = f2b(s);
        cst[tq*V_+v] = *(unsigned short*)&h;
    }
    __syncthreads();
    for (int e = tid; e < 400; e += 256)
        ((uint4*)(combh + (size_t)bid*TV_))[e] = ((const uint4*)cst)[e];
}

// K10f7: R4 two-round structure, 512-thread blocks, wave-uniform v-split:
// thread owns (c_local 0..31, ti 0..7, vh = tid>>8) with acc[13] (half of v).
// Halves VGPR (acc[25]->acc[13]) to raise waves/SIMD naturally. NO bounds cap.
__global__ __launch_bounds__(512) void k10_final7(
    const float* __restrict__ x11f, const float* __restrict__ x22f,
    const bf16* __restrict__ x3h, const bf16* __restrict__ combh,
    const float* __restrict__ beita, float* __restrict__ out)
{
    __shared__ __align__(16) char stg[25600];                 // phase1: l11|l22 ; phase2: staging
    __shared__ __align__(16) unsigned short xtl[TT2*V_*XTP3]; // 16KB
    int bid = blockIdx.x;              // n*16 + tt
    int n = bid >> 4, tt = bid & 15;
    int t0 = tt * TT2;
    int tid = threadIdx.x;
    float* l11 = (float*)stg;          // [8][8][25]
    float* l22 = (float*)(stg + 6400);
    for (int e = tid; e < 400; e += 512){
        int r = e / 50, rem = e % 50;
        ((float4*)l11)[e] = ((const float4*)(x11f + (size_t)(n*REL_+r)*TV_ + t0*V_))[rem];
        ((float4*)l22)[e] = ((const float4*)(x22f + (size_t)(n*REL_+r)*TV_ + t0*V_))[rem];
    }
    __syncthreads();
    for (int e = tid; e < TT2*VV_; e += 512){
        int ti = e / VV_, uv = e % VV_;
        int u = uv / V_, v = uv % V_;
        float s = 0.f;
        #pragma unroll
        for (int r = 0; r < REL_; ++r)
            s = fmaf(l11[r*200 + ti*V_ + u], l22[r*200 + ti*V_ + v], s);
        bf16 h = f2b(ftanh(s * 0.125f));
        xtl[ti*(V_*XTP3) + u*XTP3 + v] = *(unsigned short*)&h;
    }
    float bt = beita[0];
    int vh = tid >> 8;                 // wave-uniform: waves 0-3 -> 0, 4-7 -> 1
    int c_local = (tid >> 3) & 31;
    int ti = tid & 7;
    for (int cr = 0; cr < 2; ++cr){
        int c0 = cr*32;
        __syncthreads();   // xtl ready (cr=0) / prev store done (cr=1)
        for (int e = tid; e < 1600; e += 512){
            int cl = e / 50, w = e % 50;
            size_t base = (size_t)(n*OUT_ + c0 + cl)*TV_ + (size_t)t0*V_;
            uint4 p = (w < 25) ? ((const uint4*)(combh + base))[w]
                               : ((const uint4*)(x3h  + base))[w-25];
            *(uint4*)(stg + cl*800 + (w<25 ? w*16 : 400 + (w-25)*16)) = p;
        }
        __syncthreads();
        const unsigned short* x3row = (const unsigned short*)(stg + c_local*800 + 400) + ti*V_;
        float acc[13];
        #pragma unroll
        for (int j=0;j<13;++j) acc[j]=0.f;
        int base_s = ti*(V_*XTP3) + vh*12;   // even short index -> uint-aligned
        #pragma unroll
        for (int u=0;u<V_;++u){
            float xa = bfs(x3row[u]);        // broadcast within vh pair
            const uint* xr = (const uint*)(xtl + base_s + u*XTP3);
            uint R[7];
            #pragma unroll
            for (int k=0;k<7;++k) R[k] = xr[k];
            if (vh == 0){
                // v = 0..12: shorts base..base+12
                #pragma unroll
                for (int k=0;k<6;++k){
                    acc[2*k]   = fmaf(xa, bfu(R[k]), acc[2*k]);
                    acc[2*k+1] = fmaf(xa, bfh(R[k]), acc[2*k+1]);
                }
                acc[12] = fmaf(xa, bfu(R[6]), acc[12]);
            } else {
                // v = 13..24: shorts 12..25, j = v-13
                acc[0] = fmaf(xa, bfh(R[0]), acc[0]);
                #pragma unroll
                for (int k=1;k<6;++k){
                    acc[2*k-1] = fmaf(xa, bfu(R[k]), acc[2*k-1]);
                    acc[2*k]   = fmaf(xa, bfh(R[k]), acc[2*k]);
                }
                acc[11] = fmaf(xa, bfu(R[6]), acc[11]);
            }
        }
        const unsigned short* cmbrow =
            (const unsigned short*)(stg + c_local*800) + ti*V_ + vh*13;
        if (vh == 0){
            #pragma unroll
            for (int j=0;j<13;++j) acc[j] = fmaf(bt, acc[j], bfs(cmbrow[j]));
        } else {
            #pragma unroll
            for (int j=0;j<12;++j) acc[j] = fmaf(bt, acc[j], bfs(cmbrow[j]));
        }
        __syncthreads();   // all stage reads done before overwrite
        float* orow = (float*)(stg + c_local*800 + ti*100) + vh*13;
        if (vh == 0){
            #pragma unroll
            for (int j=0;j<13;++j) orow[j] = acc[j];
        } else {
            #pragma unroll
            for (int j=0;j<12;++j) orow[j] = acc[j];
        }
        __syncthreads();
        for (int e = tid; e < 1600; e += 512){
            int cl = e / 50, q = e % 50;
            *(float4*)(out + (size_t)(n*OUT_ + c0 + cl)*TV_ + (size_t)t0*V_ + q*4) =
                *(const float4*)(stg + cl*800 + q*16);
        }
    }
}

extern "C" void kernel_launch(void* const* d_in, const int* in_sizes, int n_in,
                              void* d_out, int out_size, void* d_ws, size_t ws_size,
                              hipStream_t stream)
{
    const float* x    = (const float*)d_in[0];
    const float* A    = (const float*)d_in[1];
    const float* w1   = (const float*)d_in[2];  const float* b1  = (const float*)d_in[3];
    const float* w2   = (const float*)d_in[4];  const float* b2  = (const float*)d_in[5];
    const float* w11  = (const float*)d_in[6];  const float* b11 = (const float*)d_in[7];
    const float* w22  = (const float*)d_in[8];  const float* b22 = (const float*)d_in[9];
    const float* w3   = (const float*)d_in[10]; const float* b3  = (const float*)d_in[11];
    const float* w4   = (const float*)d_in[12]; const float* b4  = (const float*)d_in[13];
    const float* watt = (const float*)d_in[14]; const float* batt= (const float*)d_in[15];
    const float* w5   = (const float*)d_in[16]; const float* b5  = (const float*)d_in[17];
    const float* wc1  = (const float*)d_in[18]; const float* bc1 = (const float*)d_in[19];
    const float* bng  = (const float*)d_in[20]; const float* bnb = (const float*)d_in[21];
    const float* bnm  = (const float*)d_in[22]; const float* bnv = (const float*)d_in[23];
    const float* wc2  = (const float*)d_in[24]; const float* bc2 = (const float*)d_in[25];
    const float* wsp  = (const float*)d_in[26]; const float* bsp = (const float*)d_in[27];
    const float* beita= (const float*)d_in[28];
    const int*  alpha = (const int*)d_in[29];
    float* out = (float*)d_out;

    char* wsb = (char*)d_ws;
    size_t off = 0;
    auto alloc = [&](size_t bytes)->char*{
        char* p = wsb + off;
        off += (bytes + 255) & ~(size_t)255;
        return p;
    };
    float* x1f   = (float*)alloc((size_t)N_*REL_*TV_*4);
    float* x2f   = (float*)alloc((size_t)N_*REL_*TV_*4);
    float* x11f  = (float*)alloc((size_t)N_*REL_*TV_*4);
    float* x22f  = (float*)alloc((size_t)N_*REL_*TV_*4);
    bf16*  x3h   = (bf16*) alloc((size_t)N_*OUT_*TV_*2);
    bf16*  combh = (bf16*) alloc((size_t)N_*OUT_*TV_*2);
    float* att8  = (float*)alloc((size_t)N_*REL_*VV_*4);
    float* xm    = (float*)alloc((size_t)N_*REL_*VV_*4);
    float* x3bar = (float*)alloc((size_t)N_*OUT_*V_*4);
    float* catt  = (float*)alloc((size_t)N_*OUT_*4);
    float* satt  = (float*)alloc((size_t)N_*V_*4);
    float* WTg   = (float*)alloc((size_t)96*C_*4);
    float* Bg    = (float*)alloc((size_t)96*4);
    (void)ws_size; (void)n_in; (void)in_sizes; (void)out_size;

    k0_prep<<<1, 256, 0, stream>>>(w1,b1, w2,b2, w11,b11, w22,b22, w3,b3, WTg, Bg);
    k1_convs<<<N_*50, 256, 0, stream>>>(x, WTg, Bg, x1f, x2f, x11f, x22f, x3h);
    k_x3bar<<<N_*OUT_, 128, 0, stream>>>(x3h, x3bar);
    k3_att8_xm<<<N_*REL_, 256, 0, stream>>>(x1f, x2f, w5, b5, alpha, att8, xm);
    k6_chatt2<<<N_, 256, 0, stream>>>(att8, x3bar, watt, batt,
                                      wc1, bc1, bng, bnb, bnm, bnv, wc2, bc2, catt);
    k8_satt3<<<N_, 256, 0, stream>>>(xm, A, catt, x3bar, w4, b4, wsp, bsp, satt);
    k_comb3<<<N_*OUT_, 256, 0, stream>>>(x3h, att8, xm, A, watt, batt, w4, b4,
                                         catt, satt, combh);
    k10_final7<<<N_*16, 512, 0, stream>>>(x11f, x22f, x3h, combh, beita, out);
}